// Round 3
// baseline (423.493 us; speedup 1.0000x reference)
//
#include <hip/hip_runtime.h>

// Problem constants (B,N,T,D) = (8,256,64,512)
#define Bb 8
#define Nn 256
#define Tt 64
#define Dd 512
#define NT (Nn * Tt)   // 16384

// d_out layout (all float32, concatenated in return order):
//   new_x      : Bb*NT*Dd = 67,108,864
//   new_mask   : Bb*NT    = 131,072
//   doc_seq_len: Bb       = 8
//   new_tag    : Bb*NT    = 131,072
#define O_MASK (Bb * NT * Dd)
#define O_DOC  (O_MASK + Bb * NT)
#define O_TAG  (O_DOC + Bb)

#define ROWS_PER_BLK 64                      // one full node per block
#define BLKS_PER_BATCH (NT / ROWS_PER_BLK)   // 256

typedef float v4f __attribute__((ext_vector_type(4)));

// ---------------------------------------------------------------------------
// Single fused kernel, 64-row (one-node) blocks:
//  1. shuffle-scan length[b][0..255] -> exclusive offsets in LDS (once per
//     128KB of streaming, 4x better amortized than the 16-row version)
//  2. wave 0 binary-searches src for all 64 rows; writes mask/tag/doc
//  3. streaming add, 32 f4/thread, loads batched 4-wide for MLP:
//     out[b,j,:] = gcn[b, j/T, :] + (valid ? x[b,src,:] : 0)
// All 64 rows share one node -> gcn is ONE register load, reused 32x.
// x/out are touch-once streams -> nontemporal.
// ---------------------------------------------------------------------------
__global__ __launch_bounds__(256) void fused_kernel(const int* __restrict__ length,
                                                    const int* __restrict__ tags,
                                                    const v4f* __restrict__ x,
                                                    const v4f* __restrict__ gcn,
                                                    v4f* __restrict__ out_x,
                                                    float* __restrict__ out_mask,
                                                    float* __restrict__ out_tag,
                                                    float* __restrict__ out_doc) {
    __shared__ int off[Nn + 1];
    __shared__ int wtot[4];
    __shared__ int srcs[ROWS_PER_BLK];

    const int tid  = threadIdx.x;
    const int blk  = blockIdx.x;
    const int b    = blk >> 8;                     // / BLKS_PER_BATCH
    const int node = blk & (BLKS_PER_BATCH - 1);   // == j0 / Tt
    const int j0   = node << 6;
    const int lane = tid & 63;
    const int wave = tid >> 6;

    // gcn: node-uniform for the whole block; column c = tid&127 is the same
    // for every k-iteration below -> one load, reused 32x.
    const v4f g = gcn[(b * Nn + node) * 128 + (tid & 127)];

    // --- 1. scan: per-wave shuffle inclusive scan + cross-wave combine ---
    const int v = length[b * Nn + tid];
    int inc = v;
    #pragma unroll
    for (int o = 1; o < 64; o <<= 1) {
        int t = __shfl_up(inc, o, 64);
        if (lane >= o) inc += t;
    }
    if (lane == 63) wtot[wave] = inc;
    __syncthreads();
    int wpref = 0;
    #pragma unroll
    for (int w = 0; w < 3; ++w)
        if (w < wave) wpref += wtot[w];
    off[tid] = wpref + inc - v;                    // exclusive prefix
    if (tid == 255) off[Nn] = wpref + inc;         // total = doc_seq_len
    __syncthreads();

    const int doc = off[Nn];
    if (node == 0 && tid == 0) out_doc[b] = (float)doc;

    // --- 2. wave 0 maps the block's 64 rows ---
    if (tid < ROWS_PER_BLK) {
        const int j = j0 + tid;
        int   src = -1;
        float m = 0.0f, tg = 0.0f;                 // PAD_TAG = 0
        if (j < doc) {
            int lo = 0, hi = Nn - 1;
            #pragma unroll
            for (int it = 0; it < 8; ++it) {       // 2^8 = 256 segments
                int mid = (lo + hi + 1) >> 1;
                if (off[mid] <= j) lo = mid; else hi = mid - 1;
            }
            src = lo * Tt + (j - off[lo]);
            m  = 1.0f;
            tg = (float)tags[b * NT + src];
        }
        srcs[tid] = src;
        out_mask[b * NT + j] = m;
        out_tag[b * NT + j]  = tg;
    }
    __syncthreads();

    // --- 3. streaming add: 8192 float4, 32/thread, loads batched 4-wide ---
    const int outbase = (b * NT + j0) * 128;       // f4 index < 2^24, int-safe
    const int xbbase  = (b << 14) * 128;
    const int c       = tid & 127;
    const int rh      = tid >> 7;                  // 0 or 1: row parity half
    #pragma unroll
    for (int k = 0; k < 32; k += 4) {
        int sr[4];
        #pragma unroll
        for (int u = 0; u < 4; ++u)
            sr[u] = srcs[((k + u) << 1) | rh];     // row = 2*(k+u) + rh
        v4f val[4];
        #pragma unroll
        for (int u = 0; u < 4; ++u) val[u] = g;
        #pragma unroll
        for (int u = 0; u < 4; ++u)
            if (sr[u] >= 0)                        // wave-uniform branch
                val[u] += __builtin_nontemporal_load(&x[xbbase + sr[u] * 128 + c]);
        #pragma unroll
        for (int u = 0; u < 4; ++u)
            __builtin_nontemporal_store(val[u], &out_x[outbase + (k + u) * 256 + tid]);
    }
}

extern "C" void kernel_launch(void* const* d_in, const int* in_sizes, int n_in,
                              void* d_out, int out_size, void* d_ws, size_t ws_size,
                              hipStream_t stream) {
    const float* x     = (const float*)d_in[0];  // (B,N,T,D)
    const float* x_gcn = (const float*)d_in[1];  // (B,N,D)
    // d_in[2] = mask — unused (prefix mask, fully determined by length)
    const int* length  = (const int*)d_in[3];    // (B,N)
    const int* tags    = (const int*)d_in[4];    // (B,N,T)

    float* out = (float*)d_out;

    fused_kernel<<<Bb * BLKS_PER_BATCH, 256, 0, stream>>>(
        length, tags, (const v4f*)x, (const v4f*)x_gcn,
        (v4f*)out, out + O_MASK, out + O_TAG, out + O_DOC);
}

// Round 4
// 410.567 us; speedup vs baseline: 1.0315x; 1.0315x over previous
//
#include <hip/hip_runtime.h>

// Problem constants (B,N,T,D) = (8,256,64,512)
#define Bb 8
#define Nn 256
#define Tt 64
#define Dd 512
#define NT (Nn * Tt)   // 16384

// d_out layout (all float32, concatenated in return order):
//   new_x      : Bb*NT*Dd = 67,108,864
//   new_mask   : Bb*NT    = 131,072
//   doc_seq_len: Bb       = 8
//   new_tag    : Bb*NT    = 131,072
#define O_MASK (Bb * NT * Dd)
#define O_DOC  (O_MASK + Bb * NT)
#define O_TAG  (O_DOC + Bb)

#define ROWS_PER_BLK 16            // 16 rows x 128 float4 = 2048 f4 per block
#define BLKS_PER_BATCH (NT / ROWS_PER_BLK)   // 1024

typedef float v4f __attribute__((ext_vector_type(4)));

// ---------------------------------------------------------------------------
// Single fused kernel (R2 structure: 8192 small blocks for dynamic load
// balancing — R3 showed one-resident-generation 64-row blocks tail-stall).
// Per block (256 thr, 16 output rows of one batch):
//  1. shuffle-scan length[b][0..255] -> exclusive offsets in LDS (2 barriers)
//  2. binary-search src row for each of the 16 rows; write mask/tag/doc
//  3. streaming add, loads batched 4-wide for memory-level parallelism:
//     out[b,j,:] = gcn[b, j/T, :] + (valid ? x[b,src,:] : 0)
// All 16 rows share one node -> gcn is ONE register load, reused 8x.
// x/out are touch-once streams -> nontemporal.
// ---------------------------------------------------------------------------
__global__ __launch_bounds__(256) void fused_kernel(const int* __restrict__ length,
                                                    const int* __restrict__ tags,
                                                    const v4f* __restrict__ x,
                                                    const v4f* __restrict__ gcn,
                                                    v4f* __restrict__ out_x,
                                                    float* __restrict__ out_mask,
                                                    float* __restrict__ out_tag,
                                                    float* __restrict__ out_doc) {
    __shared__ int off[Nn + 1];
    __shared__ int wtot[4];
    __shared__ int srcs[ROWS_PER_BLK];

    const int tid  = threadIdx.x;
    const int blk  = blockIdx.x;
    const int b    = blk >> 10;                    // / BLKS_PER_BATCH
    const int j0   = (blk & (BLKS_PER_BATCH - 1)) << 4;
    const int lane = tid & 63;
    const int wave = tid >> 6;

    // gcn: node-uniform for the block; column c = tid&127 is the same for
    // every k-iteration below -> one load, reused 8x.
    const int node0 = j0 >> 6;
    const v4f g = gcn[(b * Nn + node0) * 128 + (tid & 127)];

    // --- 1. scan: per-wave shuffle inclusive scan + cross-wave combine ---
    const int v = length[b * Nn + tid];
    int inc = v;
    #pragma unroll
    for (int o = 1; o < 64; o <<= 1) {
        int t = __shfl_up(inc, o, 64);
        if (lane >= o) inc += t;
    }
    if (lane == 63) wtot[wave] = inc;
    __syncthreads();
    int wpref = 0;
    #pragma unroll
    for (int w = 0; w < 3; ++w)
        if (w < wave) wpref += wtot[w];
    off[tid] = wpref + inc - v;                    // exclusive prefix
    if (tid == 255) off[Nn] = wpref + inc;         // total = doc_seq_len
    __syncthreads();

    const int doc = off[Nn];
    if ((blk & (BLKS_PER_BATCH - 1)) == 0 && tid == 0) out_doc[b] = (float)doc;

    // --- 2. map the block's 16 rows ---
    if (tid < ROWS_PER_BLK) {
        const int j = j0 + tid;
        int   src = -1;
        float m = 0.0f, tg = 0.0f;                 // PAD_TAG = 0
        if (j < doc) {
            int lo = 0, hi = Nn - 1;
            #pragma unroll
            for (int it = 0; it < 8; ++it) {       // 2^8 = 256 segments
                int mid = (lo + hi + 1) >> 1;
                if (off[mid] <= j) lo = mid; else hi = mid - 1;
            }
            src = lo * Tt + (j - off[lo]);
            m  = 1.0f;
            tg = (float)tags[b * NT + src];
        }
        srcs[tid] = src;
        out_mask[b * NT + j] = m;
        out_tag[b * NT + j]  = tg;
    }
    __syncthreads();

    // --- 3. streaming add: 2048 float4, 8/thread, loads batched 4-wide ---
    const int outbase = (b * NT + j0) * 128;       // f4 index < 2^24, int-safe
    const int xbbase  = (b << 14) * 128;
    const int c       = tid & 127;
    const int rh      = tid >> 7;                  // 0 or 1: row parity half
    #pragma unroll
    for (int k = 0; k < 8; k += 4) {
        int sr[4];
        #pragma unroll
        for (int u = 0; u < 4; ++u)
            sr[u] = srcs[((k + u) << 1) | rh];     // row = 2*(k+u) + rh
        v4f val[4];
        #pragma unroll
        for (int u = 0; u < 4; ++u) val[u] = g;
        #pragma unroll
        for (int u = 0; u < 4; ++u)
            if (sr[u] >= 0)
                val[u] += __builtin_nontemporal_load(&x[xbbase + sr[u] * 128 + c]);
        #pragma unroll
        for (int u = 0; u < 4; ++u)
            __builtin_nontemporal_store(val[u], &out_x[outbase + (k + u) * 256 + tid]);
    }
}

extern "C" void kernel_launch(void* const* d_in, const int* in_sizes, int n_in,
                              void* d_out, int out_size, void* d_ws, size_t ws_size,
                              hipStream_t stream) {
    const float* x     = (const float*)d_in[0];  // (B,N,T,D)
    const float* x_gcn = (const float*)d_in[1];  // (B,N,D)
    // d_in[2] = mask — unused (prefix mask, fully determined by length)
    const int* length  = (const int*)d_in[3];    // (B,N)
    const int* tags    = (const int*)d_in[4];    // (B,N,T)

    float* out = (float*)d_out;

    fused_kernel<<<Bb * BLKS_PER_BATCH, 256, 0, stream>>>(
        length, tags, (const v4f*)x, (const v4f*)x_gcn,
        (v4f*)out, out + O_MASK, out + O_TAG, out + O_DOC);
}